// Round 5
// baseline (170.213 us; speedup 1.0000x reference)
//
#include <hip/hip_runtime.h>
#include <hip/hip_bf16.h>
#include <stdint.h>
#include <type_traits>

#define BS 4
#define LEN 5440
#define ROWS (BS * LEN)     // 21760 = 340 * 64

typedef __bf16 bf16;
typedef _Float16 f16;
typedef __bf16 bf16x2 __attribute__((ext_vector_type(2)));
typedef __bf16 bf16x4 __attribute__((ext_vector_type(4)));
typedef __bf16 bf16x8 __attribute__((ext_vector_type(8)));
typedef _Float16 f16x8 __attribute__((ext_vector_type(8)));
typedef float f32x4 __attribute__((ext_vector_type(4)));

// ---------------------------------------------------------------------------
// Weight prep: 64x64 LDS transpose -> bf16 weights in MFMA-fragment order:
// chunk for (col c, k-chunk kc) at ((c>>4)*32 + kc)*16 + (c&15). 57 blocks.
// ---------------------------------------------------------------------------
__global__ __launch_bounds__(256) void prep_weights(
    const float* __restrict__ vproj_w, const float* __restrict__ off_w,
    const float* __restrict__ attn_w, const float* __restrict__ out_w,
    const float* __restrict__ off_b, const float* __restrict__ attn_b,
    bf16* __restrict__ bt_v, bf16* __restrict__ bt_oa, bf16* __restrict__ bt_out,
    float* __restrict__ bias_oa)
{
    const int blk = blockIdx.x;
    const int t = threadIdx.x;
    if (blk == 56) {
        bias_oa[t] = off_b[t];
        if (t < 128) bias_oa[256 + t] = attn_b[t];
        return;
    }
    const float* W; bf16* BT; int N, tn, tk, cbase;
    if (blk < 16)      { W = vproj_w; BT = bt_v;   N = 256; tk = blk >> 2;        tn = blk & 3;        cbase = 0; }
    else if (blk < 32) { W = off_w;   BT = bt_oa;  N = 256; tk = (blk - 16) >> 2; tn = (blk - 16) & 3; cbase = 0; }
    else if (blk < 40) { W = attn_w;  BT = bt_oa;  N = 128; tk = (blk - 32) >> 1; tn = (blk - 32) & 1; cbase = 256; }
    else               { W = out_w;   BT = bt_out; N = 256; tk = (blk - 40) >> 2; tn = (blk - 40) & 3; cbase = 0; }
    const int k0 = tk * 64, n0 = tn * 64;

    __shared__ float sT[64][65];
    const int r = t >> 2;
    const int cs = (t & 3) * 16;
    const float* src = W + (size_t)(k0 + r) * N + n0 + cs;
#pragma unroll
    for (int i = 0; i < 4; ++i) {
        float4 a = *(const float4*)(src + i * 4);
        sT[r][cs + i * 4 + 0] = a.x; sT[r][cs + i * 4 + 1] = a.y;
        sT[r][cs + i * 4 + 2] = a.z; sT[r][cs + i * 4 + 3] = a.w;
    }
    __syncthreads();
    const int c = cbase + n0 + r;
    const int ng = c >> 4, cl = c & 15;
    const int kc0 = (k0 + cs) >> 3;
    bf16x8 o0, o1;
#pragma unroll
    for (int i = 0; i < 8; ++i) o0[i] = (bf16)sT[cs + i][r];
#pragma unroll
    for (int i = 0; i < 8; ++i) o1[i] = (bf16)sT[cs + 8 + i][r];
    *(bf16x8*)(BT + (size_t)(((ng * 32 + kc0) * 16 + cl) * 8)) = o0;
    *(bf16x8*)(BT + (size_t)(((ng * 32 + kc0 + 1) * 16 + cl) * 8)) = o1;
}

// ---------------------------------------------------------------------------
// GEMM body (unchanged): tile 64x128, coalesced A->LDS staging,
// fragment-ordered coalesced B->regs, conflict-free ds_read + MFMA.
// ---------------------------------------------------------------------------
template <typename AT, typename OutT>
__device__ __forceinline__ void gemm_body(
    const AT* __restrict__ A, const bf16* __restrict__ BF,
    const float* __restrict__ bias, OutT* __restrict__ C,
    int N, int n0, int m0, int tid)
{
    __shared__ bf16 sA[64 * 256];   // 32 KB

    const int wave = tid >> 6;
    const int lane = tid & 63;
    const int l15  = lane & 15;
    const int quad = lane >> 4;

    if constexpr (std::is_same_v<AT, float>) {
#pragma unroll
        for (int it = 0; it < 16; ++it) {
            const int R = wave * 16 + it;
            float4 f = *(const float4*)(A + (size_t)(m0 + R) * 256 + lane * 4);
            bf16x4 h = {(bf16)f.x, (bf16)f.y, (bf16)f.z, (bf16)f.w};
            const int ch = lane >> 1, half = lane & 1;
            *(bf16x4*)(sA + R * 256 + ((ch ^ (R & 7)) << 3) + (half << 2)) = h;
        }
    } else {
#pragma unroll
        for (int it = 0; it < 8; ++it) {
            const int R = wave * 16 + it * 2 + (lane >> 5);
            const int ch = lane & 31;
            bf16x8 h = *(const bf16x8*)(A + (size_t)(m0 + R) * 256 + ch * 8);
            *(bf16x8*)(sA + R * 256 + ((ch ^ (R & 7)) << 3)) = h;
        }
    }

    const int ng0 = (n0 >> 4) + wave * 2;
    bf16x8 bfr[2][8];
#pragma unroll
    for (int nt = 0; nt < 2; ++nt) {
        const bf16* bp = BF + (size_t)(ng0 + nt) * 4096 + lane * 8;
#pragma unroll
        for (int ki = 0; ki < 8; ++ki)
            bfr[nt][ki] = *(const bf16x8*)(bp + ki * 512);
    }

    __syncthreads();

    f32x4 acc[4][2] = {};

#pragma unroll
    for (int mt = 0; mt < 4; ++mt) {
        const int R = mt * 16 + l15;
        const bf16* ab = sA + R * 256;
        const int sw = R & 7;
        bf16x8 afr[8];
#pragma unroll
        for (int ki = 0; ki < 8; ++ki)
            afr[ki] = *(const bf16x8*)(ab + (((ki * 4 + quad) ^ sw) << 3));
#pragma unroll
        for (int ki = 0; ki < 8; ++ki) {
#pragma unroll
            for (int nt = 0; nt < 2; ++nt)
                acc[mt][nt] = __builtin_amdgcn_mfma_f32_16x16x32_bf16(
                    afr[ki], bfr[nt][ki], acc[mt][nt], 0, 0, 0);
        }
    }

#pragma unroll
    for (int mt = 0; mt < 4; ++mt) {
#pragma unroll
        for (int nt = 0; nt < 2; ++nt) {
            const int col = n0 + wave * 32 + nt * 16 + l15;
            const float bv = bias[col];
#pragma unroll
            for (int r = 0; r < 4; ++r) {
                const int rr = m0 + mt * 16 + (quad << 2) + r;
                C[(uint32_t)(rr * N + col)] = static_cast<OutT>(acc[mt][nt][r] + bv);
            }
        }
    }
}

// Front GEMMs fused: 1700 blocks = 340 m-stripes x 5 n-blocks.
// nb 0,1 -> value@vproj -> f16 v ; nb 2,3,4 -> query@[off|attn] -> bf16 oa.
__global__ __launch_bounds__(256) void gemm_front(
    const float* __restrict__ value, const float* __restrict__ query,
    const bf16* __restrict__ bt_v, const bf16* __restrict__ bt_oa,
    const float* __restrict__ bias_v, const float* __restrict__ bias_oa,
    f16* __restrict__ v_h, bf16* __restrict__ oa_bf)
{
    const int bx = blockIdx.x;
    const int m = bx / 5, nb = bx % 5;
    if (nb < 2)
        gemm_body<float, f16>(value, bt_v, bias_v, v_h, 256, nb * 128, m * 64, threadIdx.x);
    else
        gemm_body<float, bf16>(query, bt_oa, bias_oa, oa_bf, 384, (nb - 2) * 128, m * 64, threadIdx.x);
}

__global__ __launch_bounds__(256) void gemm_back(
    const bf16* __restrict__ pre, const bf16* __restrict__ bt_out,
    const float* __restrict__ out_b, float* __restrict__ out)
{
    const int bx = blockIdx.x;
    gemm_body<bf16, float>(pre, bt_out, out_b, out, 256, (bx & 1) * 128,
                           (bx >> 1) * 64, threadIdx.x);
}

// ---------------------------------------------------------------------------
// Fused softmax + sampling, 8 queries/block.
// Phase 1: per-item (q,h,pt) softmax via 16-lane shfl_xor butterfly +
//          tap weights/indices -> LDS. NO min-waves launch_bounds hint
//          (it forced 40 VGPR + scratch spill; R2/R3 evidence).
// Phase 2: wave = 16 (q,h) groups; lane = (group, 16B chunk). Latency-bound
//          per R4 counters (0.44 req/cyc/CU vs ~1 ceiling; Little's law
//          matches 12 waves x ~8 inflight / ~350cyc). Fix: batch 4 points
//          -> issue 16 gathers (64 VGPR of f16x8) before their 128 FMAs.
// ---------------------------------------------------------------------------
__global__ __launch_bounds__(256) void msda_sample(
    const f16* __restrict__ v,         // [BS][LEN][256] f16
    const float* __restrict__ ref_pts, // [BS][LEN][4][2]
    const bf16* __restrict__ oa,       // [BS][LEN][384]
    bf16* __restrict__ pre)            // [BS][LEN][256]
{
    const int ib = blockIdx.x;          // [0, 2720)
    const int b  = (ib & 7) >> 1;       // batch per XCD-pair (L2 locality)
    const int qg = ((ib >> 3) << 1) + (ib & 1);   // [0, 680)
    const int q0 = qg * 8;
    const int tid = threadIdx.x;

    __shared__ float4  s_tw[1088];      // [64 (q,h)][16 pt] stride 17 (bank-safe)
    __shared__ ushort4 s_to[1088];      // spatial idx (pre-<<9), 13 bits

    const uint32_t rowbase = (uint32_t)(b * LEN + q0);

    // Phase 1: 1024 items (q,h,pt), 4 per thread. The 16 pts of one (q,h)
    // sit on 16 consecutive lanes -> softmax via shfl_xor butterfly.
#pragma unroll
    for (int it = 0; it < 4; ++it) {
        const int item = tid + it * 256;
        const int g  = item >> 4;         // (qi*8 + h), 0..63
        const int qi = item >> 7;
        const int h  = (item >> 4) & 7;
        const int pt = item & 15;
        const int l  = pt >> 2;
        const int iw = 64 >> l;
        const int st = (l == 0) ? 0 : ((l == 1) ? 4096 : ((l == 2) ? 5120 : 5376));
        const float fiw = (float)iw;
        const uint32_t row = rowbase + qi;

        // softmax over the 16 lanes of this (q,h) group
        const float lg = (float)oa[row * 384 + 256 + h * 16 + pt];
        float mx = lg;
        mx = fmaxf(mx, __shfl_xor(mx, 1));
        mx = fmaxf(mx, __shfl_xor(mx, 2));
        mx = fmaxf(mx, __shfl_xor(mx, 4));
        mx = fmaxf(mx, __shfl_xor(mx, 8));
        const float e = __expf(lg - mx);
        float sm = e;
        sm += __shfl_xor(sm, 1);
        sm += __shfl_xor(sm, 2);
        sm += __shfl_xor(sm, 4);
        sm += __shfl_xor(sm, 8);
        const float wa = e * __builtin_amdgcn_rcpf(sm);

        bf16x2 ob = *(const bf16x2*)(oa + row * 384 + (h * 16 + pt) * 2);
        const float2 rp = *(const float2*)(ref_pts + row * 8 + l * 2);
        const float x = rp.x * fiw - 0.5f + (float)ob[0];
        const float y = rp.y * fiw - 0.5f + (float)ob[1];
        const float x0f = floorf(x), y0f = floorf(y);
        const int x0 = (int)x0f, y0 = (int)y0f;
        const int x1 = x0 + 1, y1 = y0 + 1;
        const float fx = x - x0f, fy = y - y0f;
        const float w00 = (1.f - fx) * (1.f - fy) * wa;
        const float w10 = (1.f - fx) * fy * wa;
        const float w01 = fx * (1.f - fy) * wa;
        const float w11 = fx * fy * wa;
        const bool xi0 = (x0 >= 0) & (x0 < iw);
        const bool xi1 = (x1 >= 0) & (x1 < iw);
        const bool yi0 = (y0 >= 0) & (y0 < iw);
        const bool yi1 = (y1 >= 0) & (y1 < iw);
        const int xc0 = min(max(x0, 0), iw - 1), xc1 = min(max(x1, 0), iw - 1);
        const int yc0 = min(max(y0, 0), iw - 1), yc1 = min(max(y1, 0), iw - 1);
        s_tw[g * 17 + pt] = make_float4((xi0 & yi0) ? w00 : 0.f, (xi0 & yi1) ? w10 : 0.f,
                                        (xi1 & yi0) ? w01 : 0.f, (xi1 & yi1) ? w11 : 0.f);
        s_to[g * 17 + pt] = make_ushort4((unsigned short)(st + yc0 * iw + xc0),
                                         (unsigned short)(st + yc1 * iw + xc0),
                                         (unsigned short)(st + yc0 * iw + xc1),
                                         (unsigned short)(st + yc1 * iw + xc1));
    }
    __syncthreads();

    // Phase 2: wave w -> groups w*16..+15 (queries w*2, w*2+1);
    // lane: gl = lane>>2 (group), c4 = lane&3 (16B chunk = 8 channels).
    // 4-point batches: 16 gathers issued back-to-back, then 128 FMAs.
    const int wave = tid >> 6;
    const int lane = tid & 63;
    const int gl = lane >> 2, c4 = lane & 3;
    const int g = wave * 16 + gl;
    const int qi = g >> 3, h = g & 7;
    const char* vbc = (const char*)v + (uint32_t)b * (LEN * 512)
                    + (uint32_t)(h * 64 + c4 * 16);
    const int base = g * 17;

    float acc[8] = {};

#define LD(o_) (*(const f16x8*)(vbc + ((uint32_t)(o_) << 9)))
#define FMA8(d_, w_) { \
    _Pragma("unroll") \
    for (int j = 0; j < 8; ++j) acc[j] = fmaf((float)d_[j], (w_), acc[j]); }

#pragma unroll
    for (int ptb = 0; ptb < 4; ++ptb) {
        const float4  w0 = s_tw[base + ptb * 4 + 0];
        const float4  w1 = s_tw[base + ptb * 4 + 1];
        const float4  w2 = s_tw[base + ptb * 4 + 2];
        const float4  w3 = s_tw[base + ptb * 4 + 3];
        const ushort4 o0 = s_to[base + ptb * 4 + 0];
        const ushort4 o1 = s_to[base + ptb * 4 + 1];
        const ushort4 o2 = s_to[base + ptb * 4 + 2];
        const ushort4 o3 = s_to[base + ptb * 4 + 3];
        // issue all 16 gathers of this batch
        f16x8 d00 = LD(o0.x), d01 = LD(o0.y), d02 = LD(o0.z), d03 = LD(o0.w);
        f16x8 d10 = LD(o1.x), d11 = LD(o1.y), d12 = LD(o1.z), d13 = LD(o1.w);
        f16x8 d20 = LD(o2.x), d21 = LD(o2.y), d22 = LD(o2.z), d23 = LD(o2.w);
        f16x8 d30 = LD(o3.x), d31 = LD(o3.y), d32 = LD(o3.z), d33 = LD(o3.w);
        // consume
        FMA8(d00, w0.x) FMA8(d01, w0.y) FMA8(d02, w0.z) FMA8(d03, w0.w)
        FMA8(d10, w1.x) FMA8(d11, w1.y) FMA8(d12, w1.z) FMA8(d13, w1.w)
        FMA8(d20, w2.x) FMA8(d21, w2.y) FMA8(d22, w2.z) FMA8(d23, w2.w)
        FMA8(d30, w3.x) FMA8(d31, w3.y) FMA8(d32, w3.z) FMA8(d33, w3.w)
    }
#undef LD
#undef FMA8

    bf16x8 o;
#pragma unroll
    for (int j = 0; j < 8; ++j) o[j] = (bf16)acc[j];
    *(bf16x8*)(pre + (rowbase + qi) * 256 + h * 32 + c4 * 8) = o;
}

// ---------------------------------------------------------------------------
// Launch: 4 dispatches
// ---------------------------------------------------------------------------
extern "C" void kernel_launch(void* const* d_in, const int* in_sizes, int n_in,
                              void* d_out, int out_size, void* d_ws, size_t ws_size,
                              hipStream_t stream) {
    const float* query   = (const float*)d_in[0];
    const float* ref_pts = (const float*)d_in[1];
    const float* value   = (const float*)d_in[2];
    const float* vproj_w = (const float*)d_in[5];
    const float* vproj_b = (const float*)d_in[6];
    const float* off_w   = (const float*)d_in[7];
    const float* off_b   = (const float*)d_in[8];
    const float* attn_w  = (const float*)d_in[9];
    const float* attn_b  = (const float*)d_in[10];
    const float* out_w   = (const float*)d_in[11];
    const float* out_b   = (const float*)d_in[12];
    float* out = (float*)d_out;

    bf16* ws = (bf16*)d_ws;
    f16*  v_h     = (f16*)ws;                          // ROWS*256 (f16)
    bf16* oa_bf   = ws     + (size_t)ROWS * 256;       // ROWS*384
    bf16* pre_bf  = oa_bf  + (size_t)ROWS * 384;       // ROWS*256
    bf16* bt_v    = pre_bf + (size_t)ROWS * 256;       // 256*256 (frag order)
    bf16* bt_oa   = bt_v   + 256 * 256;                // 384*256 (frag order)
    bf16* bt_out  = bt_oa  + 384 * 256;                // 256*256 (frag order)
    float* bias_oa = (float*)(bt_out + 256 * 256);     // 384 f32

    dim3 blk(256);

    prep_weights<<<dim3(57), blk, 0, stream>>>(vproj_w, off_w, attn_w, out_w,
                                               off_b, attn_b, bt_v, bt_oa, bt_out, bias_oa);

    gemm_front<<<dim3(1700), blk, 0, stream>>>(value, query, bt_v, bt_oa,
                                               vproj_b, bias_oa, v_h, oa_bf);

    msda_sample<<<dim3(2720), blk, 0, stream>>>(v_h, ref_pts, oa_bf, pre_bf);

    gemm_back<<<dim3(680), blk, 0, stream>>>(pre_bf, bt_out, out_b, out);
}

// Round 6
// 169.622 us; speedup vs baseline: 1.0035x; 1.0035x over previous
//
#include <hip/hip_runtime.h>
#include <hip/hip_bf16.h>
#include <stdint.h>
#include <type_traits>

#define BS 4
#define LEN 5440
#define ROWS (BS * LEN)     // 21760 = 340 * 64

typedef __bf16 bf16;
typedef _Float16 f16;
typedef __bf16 bf16x2 __attribute__((ext_vector_type(2)));
typedef __bf16 bf16x4 __attribute__((ext_vector_type(4)));
typedef __bf16 bf16x8 __attribute__((ext_vector_type(8)));
typedef _Float16 f16x8 __attribute__((ext_vector_type(8)));
typedef float f32x4 __attribute__((ext_vector_type(4)));

// ---------------------------------------------------------------------------
// Weight prep: 64x64 LDS transpose -> bf16 weights in MFMA-fragment order:
// chunk for (col c, k-chunk kc) at ((c>>4)*32 + kc)*16 + (c&15). 57 blocks.
// ---------------------------------------------------------------------------
__global__ __launch_bounds__(256) void prep_weights(
    const float* __restrict__ vproj_w, const float* __restrict__ off_w,
    const float* __restrict__ attn_w, const float* __restrict__ out_w,
    const float* __restrict__ off_b, const float* __restrict__ attn_b,
    bf16* __restrict__ bt_v, bf16* __restrict__ bt_oa, bf16* __restrict__ bt_out,
    float* __restrict__ bias_oa)
{
    const int blk = blockIdx.x;
    const int t = threadIdx.x;
    if (blk == 56) {
        bias_oa[t] = off_b[t];
        if (t < 128) bias_oa[256 + t] = attn_b[t];
        return;
    }
    const float* W; bf16* BT; int N, tn, tk, cbase;
    if (blk < 16)      { W = vproj_w; BT = bt_v;   N = 256; tk = blk >> 2;        tn = blk & 3;        cbase = 0; }
    else if (blk < 32) { W = off_w;   BT = bt_oa;  N = 256; tk = (blk - 16) >> 2; tn = (blk - 16) & 3; cbase = 0; }
    else if (blk < 40) { W = attn_w;  BT = bt_oa;  N = 128; tk = (blk - 32) >> 1; tn = (blk - 32) & 1; cbase = 256; }
    else               { W = out_w;   BT = bt_out; N = 256; tk = (blk - 40) >> 2; tn = (blk - 40) & 3; cbase = 0; }
    const int k0 = tk * 64, n0 = tn * 64;

    __shared__ float sT[64][65];
    const int r = t >> 2;
    const int cs = (t & 3) * 16;
    const float* src = W + (size_t)(k0 + r) * N + n0 + cs;
#pragma unroll
    for (int i = 0; i < 4; ++i) {
        float4 a = *(const float4*)(src + i * 4);
        sT[r][cs + i * 4 + 0] = a.x; sT[r][cs + i * 4 + 1] = a.y;
        sT[r][cs + i * 4 + 2] = a.z; sT[r][cs + i * 4 + 3] = a.w;
    }
    __syncthreads();
    const int c = cbase + n0 + r;
    const int ng = c >> 4, cl = c & 15;
    const int kc0 = (k0 + cs) >> 3;
    bf16x8 o0, o1;
#pragma unroll
    for (int i = 0; i < 8; ++i) o0[i] = (bf16)sT[cs + i][r];
#pragma unroll
    for (int i = 0; i < 8; ++i) o1[i] = (bf16)sT[cs + 8 + i][r];
    *(bf16x8*)(BT + (size_t)(((ng * 32 + kc0) * 16 + cl) * 8)) = o0;
    *(bf16x8*)(BT + (size_t)(((ng * 32 + kc0 + 1) * 16 + cl) * 8)) = o1;
}

// ---------------------------------------------------------------------------
// Merged GEMM body: stage the 64x256 A-stripe ONCE, then loop NH n-halves
// of 128 cols each {B-frag load -> 64 MFMA/wave -> biased store}.
// (R6: previously each n-half was its own block -> A staged 2-3x; A fetch
// 111.5 MB -> 44.6 MB and staging VALU / 2.5.)
// ---------------------------------------------------------------------------
template <typename AT, typename OutT, int NH>
__device__ __forceinline__ void gemm_multi(
    const AT* __restrict__ A, const bf16* __restrict__ BF,
    const float* __restrict__ bias, OutT* __restrict__ C,
    int N, int m0, int tid)
{
    __shared__ bf16 sA[64 * 256];   // 32 KB

    const int wave = tid >> 6;
    const int lane = tid & 63;
    const int l15  = lane & 15;
    const int quad = lane >> 4;

    if constexpr (std::is_same_v<AT, float>) {
#pragma unroll
        for (int it = 0; it < 16; ++it) {
            const int R = wave * 16 + it;
            float4 f = *(const float4*)(A + (size_t)(m0 + R) * 256 + lane * 4);
            bf16x4 h = {(bf16)f.x, (bf16)f.y, (bf16)f.z, (bf16)f.w};
            const int ch = lane >> 1, half = lane & 1;
            *(bf16x4*)(sA + R * 256 + ((ch ^ (R & 7)) << 3) + (half << 2)) = h;
        }
    } else {
#pragma unroll
        for (int it = 0; it < 8; ++it) {
            const int R = wave * 16 + it * 2 + (lane >> 5);
            const int ch = lane & 31;
            bf16x8 h = *(const bf16x8*)(A + (size_t)(m0 + R) * 256 + ch * 8);
            *(bf16x8*)(sA + R * 256 + ((ch ^ (R & 7)) << 3)) = h;
        }
    }

    __syncthreads();

    for (int nh = 0; nh < NH; ++nh) {
        const int n0 = nh * 128;
        const int ng0 = (n0 >> 4) + wave * 2;
        bf16x8 bfr[2][8];
#pragma unroll
        for (int nt = 0; nt < 2; ++nt) {
            const bf16* bp = BF + (size_t)(ng0 + nt) * 4096 + lane * 8;
#pragma unroll
            for (int ki = 0; ki < 8; ++ki)
                bfr[nt][ki] = *(const bf16x8*)(bp + ki * 512);
        }

        f32x4 acc[4][2] = {};

#pragma unroll
        for (int mt = 0; mt < 4; ++mt) {
            const int R = mt * 16 + l15;
            const bf16* ab = sA + R * 256;
            const int sw = R & 7;
            bf16x8 afr[8];
#pragma unroll
            for (int ki = 0; ki < 8; ++ki)
                afr[ki] = *(const bf16x8*)(ab + (((ki * 4 + quad) ^ sw) << 3));
#pragma unroll
            for (int ki = 0; ki < 8; ++ki) {
#pragma unroll
                for (int nt = 0; nt < 2; ++nt)
                    acc[mt][nt] = __builtin_amdgcn_mfma_f32_16x16x32_bf16(
                        afr[ki], bfr[nt][ki], acc[mt][nt], 0, 0, 0);
            }
        }

#pragma unroll
        for (int mt = 0; mt < 4; ++mt) {
#pragma unroll
            for (int nt = 0; nt < 2; ++nt) {
                const int col = n0 + wave * 32 + nt * 16 + l15;
                const float bv = bias[col];
#pragma unroll
                for (int r = 0; r < 4; ++r) {
                    const int rr = m0 + mt * 16 + (quad << 2) + r;
                    C[(uint32_t)(rr * N + col)] = static_cast<OutT>(acc[mt][nt][r] + bv);
                }
            }
        }
    }
}

// Front GEMMs: 680 blocks = 340 m-stripes x {value (NH=2), query (NH=3)}.
__global__ __launch_bounds__(256) void gemm_front(
    const float* __restrict__ value, const float* __restrict__ query,
    const bf16* __restrict__ bt_v, const bf16* __restrict__ bt_oa,
    const float* __restrict__ bias_v, const float* __restrict__ bias_oa,
    f16* __restrict__ v_h, bf16* __restrict__ oa_bf)
{
    const int bx = blockIdx.x;
    const int m = bx >> 1;
    if ((bx & 1) == 0)
        gemm_multi<float, f16, 2>(value, bt_v, bias_v, v_h, 256, m * 64, threadIdx.x);
    else
        gemm_multi<float, bf16, 3>(query, bt_oa, bias_oa, oa_bf, 384, m * 64, threadIdx.x);
}

// Back GEMM: 340 blocks, NH=2, A (pre) staged once.
__global__ __launch_bounds__(256) void gemm_back(
    const bf16* __restrict__ pre, const bf16* __restrict__ bt_out,
    const float* __restrict__ out_b, float* __restrict__ out)
{
    gemm_multi<bf16, float, 2>(pre, bt_out, out_b, out, 256,
                               blockIdx.x * 64, threadIdx.x);
}

// ---------------------------------------------------------------------------
// Fused softmax + sampling, 8 queries/block.
// Phase 1: per-item (q,h,pt) softmax via 16-lane shfl_xor butterfly +
//          tap weights/indices -> LDS. NO min-waves launch_bounds hint
//          (it forced 40 VGPR + scratch spill; R2/R3 evidence).
// Phase 2: simple TAP loop, ~41 us; near-plateau (R5 batch-MLP test: no
//          change). L2-BW floor est ~21 us.
// ---------------------------------------------------------------------------
__global__ __launch_bounds__(256) void msda_sample(
    const f16* __restrict__ v,         // [BS][LEN][256] f16
    const float* __restrict__ ref_pts, // [BS][LEN][4][2]
    const bf16* __restrict__ oa,       // [BS][LEN][384]
    bf16* __restrict__ pre)            // [BS][LEN][256]
{
    const int ib = blockIdx.x;          // [0, 2720)
    const int b  = (ib & 7) >> 1;       // batch per XCD-pair (L2 locality)
    const int qg = ((ib >> 3) << 1) + (ib & 1);   // [0, 680)
    const int q0 = qg * 8;
    const int tid = threadIdx.x;

    __shared__ float4  s_tw[1088];      // [64 (q,h)][16 pt] stride 17 (bank-safe)
    __shared__ ushort4 s_to[1088];      // spatial idx (pre-<<9), 13 bits

    const uint32_t rowbase = (uint32_t)(b * LEN + q0);

    // Phase 1: 1024 items (q,h,pt), 4 per thread. The 16 pts of one (q,h)
    // sit on 16 consecutive lanes -> softmax via shfl_xor butterfly.
#pragma unroll
    for (int it = 0; it < 4; ++it) {
        const int item = tid + it * 256;
        const int g  = item >> 4;         // (qi*8 + h), 0..63
        const int qi = item >> 7;
        const int h  = (item >> 4) & 7;
        const int pt = item & 15;
        const int l  = pt >> 2;
        const int iw = 64 >> l;
        const int st = (l == 0) ? 0 : ((l == 1) ? 4096 : ((l == 2) ? 5120 : 5376));
        const float fiw = (float)iw;
        const uint32_t row = rowbase + qi;

        // softmax over the 16 lanes of this (q,h) group
        const float lg = (float)oa[row * 384 + 256 + h * 16 + pt];
        float mx = lg;
        mx = fmaxf(mx, __shfl_xor(mx, 1));
        mx = fmaxf(mx, __shfl_xor(mx, 2));
        mx = fmaxf(mx, __shfl_xor(mx, 4));
        mx = fmaxf(mx, __shfl_xor(mx, 8));
        const float e = __expf(lg - mx);
        float sm = e;
        sm += __shfl_xor(sm, 1);
        sm += __shfl_xor(sm, 2);
        sm += __shfl_xor(sm, 4);
        sm += __shfl_xor(sm, 8);
        const float wa = e * __builtin_amdgcn_rcpf(sm);

        bf16x2 ob = *(const bf16x2*)(oa + row * 384 + (h * 16 + pt) * 2);
        const float2 rp = *(const float2*)(ref_pts + row * 8 + l * 2);
        const float x = rp.x * fiw - 0.5f + (float)ob[0];
        const float y = rp.y * fiw - 0.5f + (float)ob[1];
        const float x0f = floorf(x), y0f = floorf(y);
        const int x0 = (int)x0f, y0 = (int)y0f;
        const int x1 = x0 + 1, y1 = y0 + 1;
        const float fx = x - x0f, fy = y - y0f;
        const float w00 = (1.f - fx) * (1.f - fy) * wa;
        const float w10 = (1.f - fx) * fy * wa;
        const float w01 = fx * (1.f - fy) * wa;
        const float w11 = fx * fy * wa;
        const bool xi0 = (x0 >= 0) & (x0 < iw);
        const bool xi1 = (x1 >= 0) & (x1 < iw);
        const bool yi0 = (y0 >= 0) & (y0 < iw);
        const bool yi1 = (y1 >= 0) & (y1 < iw);
        const int xc0 = min(max(x0, 0), iw - 1), xc1 = min(max(x1, 0), iw - 1);
        const int yc0 = min(max(y0, 0), iw - 1), yc1 = min(max(y1, 0), iw - 1);
        s_tw[g * 17 + pt] = make_float4((xi0 & yi0) ? w00 : 0.f, (xi0 & yi1) ? w10 : 0.f,
                                        (xi1 & yi0) ? w01 : 0.f, (xi1 & yi1) ? w11 : 0.f);
        s_to[g * 17 + pt] = make_ushort4((unsigned short)(st + yc0 * iw + xc0),
                                         (unsigned short)(st + yc1 * iw + xc0),
                                         (unsigned short)(st + yc0 * iw + xc1),
                                         (unsigned short)(st + yc1 * iw + xc1));
    }
    __syncthreads();

    // Phase 2: wave w -> groups w*16..+15 (queries w*2, w*2+1);
    // lane: gl = lane>>2 (group), c4 = lane&3 (16B chunk = 8 channels).
    const int wave = tid >> 6;
    const int lane = tid & 63;
    const int gl = lane >> 2, c4 = lane & 3;
    const int g = wave * 16 + gl;
    const int qi = g >> 3, h = g & 7;
    const char* vbc = (const char*)v + (uint32_t)b * (LEN * 512)
                    + (uint32_t)(h * 64 + c4 * 16);
    const int base = g * 17;

    float acc[8] = {};
#pragma unroll
    for (int pt = 0; pt < 16; ++pt) {
        const float4  w4 = s_tw[base + pt];
        const ushort4 o4 = s_to[base + pt];
#define TAP(OFF, W) { \
        f16x8 d = *(const f16x8*)(vbc + ((uint32_t)(OFF) << 9)); \
        _Pragma("unroll") \
        for (int j = 0; j < 8; ++j) acc[j] = fmaf((float)d[j], (W), acc[j]); }
        TAP(o4.x, w4.x)
        TAP(o4.y, w4.y)
        TAP(o4.z, w4.z)
        TAP(o4.w, w4.w)
#undef TAP
    }

    bf16x8 o;
#pragma unroll
    for (int j = 0; j < 8; ++j) o[j] = (bf16)acc[j];
    *(bf16x8*)(pre + (rowbase + qi) * 256 + h * 32 + c4 * 8) = o;
}

// ---------------------------------------------------------------------------
// Launch: 4 dispatches
// ---------------------------------------------------------------------------
extern "C" void kernel_launch(void* const* d_in, const int* in_sizes, int n_in,
                              void* d_out, int out_size, void* d_ws, size_t ws_size,
                              hipStream_t stream) {
    const float* query   = (const float*)d_in[0];
    const float* ref_pts = (const float*)d_in[1];
    const float* value   = (const float*)d_in[2];
    const float* vproj_w = (const float*)d_in[5];
    const float* vproj_b = (const float*)d_in[6];
    const float* off_w   = (const float*)d_in[7];
    const float* off_b   = (const float*)d_in[8];
    const float* attn_w  = (const float*)d_in[9];
    const float* attn_b  = (const float*)d_in[10];
    const float* out_w   = (const float*)d_in[11];
    const float* out_b   = (const float*)d_in[12];
    float* out = (float*)d_out;

    bf16* ws = (bf16*)d_ws;
    f16*  v_h     = (f16*)ws;                          // ROWS*256 (f16)
    bf16* oa_bf   = ws     + (size_t)ROWS * 256;       // ROWS*384
    bf16* pre_bf  = oa_bf  + (size_t)ROWS * 384;       // ROWS*256
    bf16* bt_v    = pre_bf + (size_t)ROWS * 256;       // 256*256 (frag order)
    bf16* bt_oa   = bt_v   + 256 * 256;                // 384*256 (frag order)
    bf16* bt_out  = bt_oa  + 384 * 256;                // 256*256 (frag order)
    float* bias_oa = (float*)(bt_out + 256 * 256);     // 384 f32

    dim3 blk(256);

    prep_weights<<<dim3(57), blk, 0, stream>>>(vproj_w, off_w, attn_w, out_w,
                                               off_b, attn_b, bt_v, bt_oa, bt_out, bias_oa);

    gemm_front<<<dim3(680), blk, 0, stream>>>(value, query, bt_v, bt_oa,
                                              vproj_b, bias_oa, v_h, oa_bf);

    msda_sample<<<dim3(2720), blk, 0, stream>>>(v_h, ref_pts, oa_bf, pre_bf);

    gemm_back<<<dim3(340), blk, 0, stream>>>(pre_bf, bt_out, out_b, out);
}

// Round 7
// 167.630 us; speedup vs baseline: 1.0154x; 1.0119x over previous
//
#include <hip/hip_runtime.h>
#include <hip/hip_bf16.h>
#include <stdint.h>
#include <type_traits>

#define BS 4
#define LEN 5440
#define ROWS (BS * LEN)     // 21760 = 340 * 64

typedef __bf16 bf16;
typedef _Float16 f16;
typedef __bf16 bf16x2 __attribute__((ext_vector_type(2)));
typedef __bf16 bf16x4 __attribute__((ext_vector_type(4)));
typedef __bf16 bf16x8 __attribute__((ext_vector_type(8)));
typedef _Float16 f16x8 __attribute__((ext_vector_type(8)));
typedef float f32x4 __attribute__((ext_vector_type(4)));

// ---------------------------------------------------------------------------
// Weight prep: 64x64 LDS transpose -> bf16 weights in MFMA-fragment order:
// chunk for (col c, k-chunk kc) at ((c>>4)*32 + kc)*16 + (c&15). 57 blocks.
// ---------------------------------------------------------------------------
__global__ __launch_bounds__(256) void prep_weights(
    const float* __restrict__ vproj_w, const float* __restrict__ off_w,
    const float* __restrict__ attn_w, const float* __restrict__ out_w,
    const float* __restrict__ off_b, const float* __restrict__ attn_b,
    bf16* __restrict__ bt_v, bf16* __restrict__ bt_oa, bf16* __restrict__ bt_out,
    float* __restrict__ bias_oa)
{
    const int blk = blockIdx.x;
    const int t = threadIdx.x;
    if (blk == 56) {
        bias_oa[t] = off_b[t];
        if (t < 128) bias_oa[256 + t] = attn_b[t];
        return;
    }
    const float* W; bf16* BT; int N, tn, tk, cbase;
    if (blk < 16)      { W = vproj_w; BT = bt_v;   N = 256; tk = blk >> 2;        tn = blk & 3;        cbase = 0; }
    else if (blk < 32) { W = off_w;   BT = bt_oa;  N = 256; tk = (blk - 16) >> 2; tn = (blk - 16) & 3; cbase = 0; }
    else if (blk < 40) { W = attn_w;  BT = bt_oa;  N = 128; tk = (blk - 32) >> 1; tn = (blk - 32) & 1; cbase = 256; }
    else               { W = out_w;   BT = bt_out; N = 256; tk = (blk - 40) >> 2; tn = (blk - 40) & 3; cbase = 0; }
    const int k0 = tk * 64, n0 = tn * 64;

    __shared__ float sT[64][65];
    const int r = t >> 2;
    const int cs = (t & 3) * 16;
    const float* src = W + (size_t)(k0 + r) * N + n0 + cs;
#pragma unroll
    for (int i = 0; i < 4; ++i) {
        float4 a = *(const float4*)(src + i * 4);
        sT[r][cs + i * 4 + 0] = a.x; sT[r][cs + i * 4 + 1] = a.y;
        sT[r][cs + i * 4 + 2] = a.z; sT[r][cs + i * 4 + 3] = a.w;
    }
    __syncthreads();
    const int c = cbase + n0 + r;
    const int ng = c >> 4, cl = c & 15;
    const int kc0 = (k0 + cs) >> 3;
    bf16x8 o0, o1;
#pragma unroll
    for (int i = 0; i < 8; ++i) o0[i] = (bf16)sT[cs + i][r];
#pragma unroll
    for (int i = 0; i < 8; ++i) o1[i] = (bf16)sT[cs + 8 + i][r];
    *(bf16x8*)(BT + (size_t)(((ng * 32 + kc0) * 16 + cl) * 8)) = o0;
    *(bf16x8*)(BT + (size_t)(((ng * 32 + kc0 + 1) * 16 + cl) * 8)) = o1;
}

// ---------------------------------------------------------------------------
// Merged GEMM body: stage the 64x256 A-stripe ONCE, then loop NH n-halves
// of 128 cols each {B-frag load -> 64 MFMA/wave -> biased store}.
// ---------------------------------------------------------------------------
template <typename AT, typename OutT, int NH>
__device__ __forceinline__ void gemm_multi(
    const AT* __restrict__ A, const bf16* __restrict__ BF,
    const float* __restrict__ bias, OutT* __restrict__ C,
    int N, int m0, int tid)
{
    __shared__ bf16 sA[64 * 256];   // 32 KB

    const int wave = tid >> 6;
    const int lane = tid & 63;
    const int l15  = lane & 15;
    const int quad = lane >> 4;

    if constexpr (std::is_same_v<AT, float>) {
#pragma unroll
        for (int it = 0; it < 16; ++it) {
            const int R = wave * 16 + it;
            float4 f = *(const float4*)(A + (size_t)(m0 + R) * 256 + lane * 4);
            bf16x4 h = {(bf16)f.x, (bf16)f.y, (bf16)f.z, (bf16)f.w};
            const int ch = lane >> 1, half = lane & 1;
            *(bf16x4*)(sA + R * 256 + ((ch ^ (R & 7)) << 3) + (half << 2)) = h;
        }
    } else {
#pragma unroll
        for (int it = 0; it < 8; ++it) {
            const int R = wave * 16 + it * 2 + (lane >> 5);
            const int ch = lane & 31;
            bf16x8 h = *(const bf16x8*)(A + (size_t)(m0 + R) * 256 + ch * 8);
            *(bf16x8*)(sA + R * 256 + ((ch ^ (R & 7)) << 3)) = h;
        }
    }

    __syncthreads();

    for (int nh = 0; nh < NH; ++nh) {
        const int n0 = nh * 128;
        const int ng0 = (n0 >> 4) + wave * 2;
        bf16x8 bfr[2][8];
#pragma unroll
        for (int nt = 0; nt < 2; ++nt) {
            const bf16* bp = BF + (size_t)(ng0 + nt) * 4096 + lane * 8;
#pragma unroll
            for (int ki = 0; ki < 8; ++ki)
                bfr[nt][ki] = *(const bf16x8*)(bp + ki * 512);
        }

        f32x4 acc[4][2] = {};

#pragma unroll
        for (int mt = 0; mt < 4; ++mt) {
            const int R = mt * 16 + l15;
            const bf16* ab = sA + R * 256;
            const int sw = R & 7;
            bf16x8 afr[8];
#pragma unroll
            for (int ki = 0; ki < 8; ++ki)
                afr[ki] = *(const bf16x8*)(ab + (((ki * 4 + quad) ^ sw) << 3));
#pragma unroll
            for (int ki = 0; ki < 8; ++ki) {
#pragma unroll
                for (int nt = 0; nt < 2; ++nt)
                    acc[mt][nt] = __builtin_amdgcn_mfma_f32_16x16x32_bf16(
                        afr[ki], bfr[nt][ki], acc[mt][nt], 0, 0, 0);
            }
        }

#pragma unroll
        for (int mt = 0; mt < 4; ++mt) {
#pragma unroll
            for (int nt = 0; nt < 2; ++nt) {
                const int col = n0 + wave * 32 + nt * 16 + l15;
                const float bv = bias[col];
#pragma unroll
                for (int r = 0; r < 4; ++r) {
                    const int rr = m0 + mt * 16 + (quad << 2) + r;
                    C[(uint32_t)(rr * N + col)] = static_cast<OutT>(acc[mt][nt][r] + bv);
                }
            }
        }
    }
}

// Front GEMMs: 680 blocks = 340 m-stripes x {value (NH=2), query (NH=3)}.
__global__ __launch_bounds__(256) void gemm_front(
    const float* __restrict__ value, const float* __restrict__ query,
    const bf16* __restrict__ bt_v, const bf16* __restrict__ bt_oa,
    const float* __restrict__ bias_v, const float* __restrict__ bias_oa,
    f16* __restrict__ v_h, bf16* __restrict__ oa_bf)
{
    const int bx = blockIdx.x;
    const int m = bx >> 1;
    if ((bx & 1) == 0)
        gemm_multi<float, f16, 2>(value, bt_v, bias_v, v_h, 256, m * 64, threadIdx.x);
    else
        gemm_multi<float, bf16, 3>(query, bt_oa, bias_oa, oa_bf, 384, m * 64, threadIdx.x);
}

// Back GEMM: 340 blocks, NH=2, A (pre) staged once.
__global__ __launch_bounds__(256) void gemm_back(
    const bf16* __restrict__ pre, const bf16* __restrict__ bt_out,
    const float* __restrict__ out_b, float* __restrict__ out)
{
    gemm_multi<bf16, float, 2>(pre, bt_out, out_b, out, 256,
                               blockIdx.x * 64, threadIdx.x);
}

// ---------------------------------------------------------------------------
// Fused softmax + sampling, 4 queries/block, 5440 blocks.
// R7: pt-halved phase 2 — lane = (ph:1, gl:3, c4:2); each lane does 8 pts
// (32 loads) instead of 16 (64); cross-half shfl_xor(32) reduce at the end.
// LDS 17.4 KB (int4 pre-shifted offsets) -> occupancy wave-capped at
// 32 waves/CU (100%) vs 24 before. No min-waves hint (R2/R3 spill lesson).
// ---------------------------------------------------------------------------
__global__ __launch_bounds__(256) void msda_sample(
    const f16* __restrict__ v,         // [BS][LEN][256] f16
    const float* __restrict__ ref_pts, // [BS][LEN][4][2]
    const bf16* __restrict__ oa,       // [BS][LEN][384]
    bf16* __restrict__ pre)            // [BS][LEN][256]
{
    const int ib = blockIdx.x;          // [0, 5440)
    const int b  = (ib & 7) >> 1;       // batch per XCD-pair (L2 locality)
    const int qg = ((ib >> 3) << 1) + (ib & 1);   // [0, 1360)
    const int q0 = qg * 4;
    const int tid = threadIdx.x;

    __shared__ float4 s_tw[544];        // [32 (q,h)][16 pt] stride 17
    __shared__ int4   s_to[544];        // byte offsets (idx<<9)

    const uint32_t rowbase = (uint32_t)(b * LEN + q0);

    // Phase 1: 512 items (q,h,pt), 2 per thread. The 16 pts of one (q,h)
    // sit on 16 consecutive lanes -> softmax via shfl_xor butterfly.
#pragma unroll
    for (int it = 0; it < 2; ++it) {
        const int item = tid + it * 256;
        const int g  = item >> 4;         // (qi*8 + h), 0..31
        const int qi = item >> 7;         // 0..3
        const int h  = (item >> 4) & 7;
        const int pt = item & 15;
        const int l  = pt >> 2;
        const int iw = 64 >> l;
        const int st = (l == 0) ? 0 : ((l == 1) ? 4096 : ((l == 2) ? 5120 : 5376));
        const float fiw = (float)iw;
        const uint32_t row = rowbase + qi;

        // softmax over the 16 lanes of this (q,h) group
        const float lg = (float)oa[row * 384 + 256 + h * 16 + pt];
        float mx = lg;
        mx = fmaxf(mx, __shfl_xor(mx, 1));
        mx = fmaxf(mx, __shfl_xor(mx, 2));
        mx = fmaxf(mx, __shfl_xor(mx, 4));
        mx = fmaxf(mx, __shfl_xor(mx, 8));
        const float e = __expf(lg - mx);
        float sm = e;
        sm += __shfl_xor(sm, 1);
        sm += __shfl_xor(sm, 2);
        sm += __shfl_xor(sm, 4);
        sm += __shfl_xor(sm, 8);
        const float wa = e * __builtin_amdgcn_rcpf(sm);

        bf16x2 ob = *(const bf16x2*)(oa + row * 384 + (h * 16 + pt) * 2);
        const float2 rp = *(const float2*)(ref_pts + row * 8 + l * 2);
        const float x = rp.x * fiw - 0.5f + (float)ob[0];
        const float y = rp.y * fiw - 0.5f + (float)ob[1];
        const float x0f = floorf(x), y0f = floorf(y);
        const int x0 = (int)x0f, y0 = (int)y0f;
        const int x1 = x0 + 1, y1 = y0 + 1;
        const float fx = x - x0f, fy = y - y0f;
        const float w00 = (1.f - fx) * (1.f - fy) * wa;
        const float w10 = (1.f - fx) * fy * wa;
        const float w01 = fx * (1.f - fy) * wa;
        const float w11 = fx * fy * wa;
        const bool xi0 = (x0 >= 0) & (x0 < iw);
        const bool xi1 = (x1 >= 0) & (x1 < iw);
        const bool yi0 = (y0 >= 0) & (y0 < iw);
        const bool yi1 = (y1 >= 0) & (y1 < iw);
        const int xc0 = min(max(x0, 0), iw - 1), xc1 = min(max(x1, 0), iw - 1);
        const int yc0 = min(max(y0, 0), iw - 1), yc1 = min(max(y1, 0), iw - 1);
        s_tw[g * 17 + pt] = make_float4((xi0 & yi0) ? w00 : 0.f, (xi0 & yi1) ? w10 : 0.f,
                                        (xi1 & yi0) ? w01 : 0.f, (xi1 & yi1) ? w11 : 0.f);
        s_to[g * 17 + pt] = make_int4((st + yc0 * iw + xc0) << 9,
                                      (st + yc1 * iw + xc0) << 9,
                                      (st + yc0 * iw + xc1) << 9,
                                      (st + yc1 * iw + xc1) << 9);
    }
    __syncthreads();

    // Phase 2: lane = ph*32 + gl*4 + c4. Wave w owns groups w*8..w*8+7;
    // half ph handles pts ph*8..ph*8+7; cross-half reduce at the end.
    const int wave = tid >> 6;
    const int lane = tid & 63;
    const int ph = lane >> 5;
    const int gl = (lane >> 2) & 7;
    const int c4 = lane & 3;
    const int g = wave * 8 + gl;        // 0..31
    const int qi = g >> 3, h = g & 7;
    const char* vbc = (const char*)v + (uint32_t)b * (LEN * 512)
                    + (uint32_t)(h * 64 + c4 * 16);
    const int base = g * 17 + ph * 8;

    float acc[8] = {};
#pragma unroll
    for (int pt = 0; pt < 8; ++pt) {
        const float4 w4 = s_tw[base + pt];
        const int4   o4 = s_to[base + pt];
#define TAP(OFF, W) { \
        f16x8 d = *(const f16x8*)(vbc + (uint32_t)(OFF)); \
        _Pragma("unroll") \
        for (int j = 0; j < 8; ++j) acc[j] = fmaf((float)d[j], (W), acc[j]); }
        TAP(o4.x, w4.x)
        TAP(o4.y, w4.y)
        TAP(o4.z, w4.z)
        TAP(o4.w, w4.w)
#undef TAP
    }

    // combine the two pt-halves
#pragma unroll
    for (int j = 0; j < 8; ++j) acc[j] += __shfl_xor(acc[j], 32);

    if (ph == 0) {
        bf16x8 o;
#pragma unroll
        for (int j = 0; j < 8; ++j) o[j] = (bf16)acc[j];
        *(bf16x8*)(pre + (rowbase + qi) * 256 + h * 32 + c4 * 8) = o;
    }
}

// ---------------------------------------------------------------------------
// Launch: 4 dispatches
// ---------------------------------------------------------------------------
extern "C" void kernel_launch(void* const* d_in, const int* in_sizes, int n_in,
                              void* d_out, int out_size, void* d_ws, size_t ws_size,
                              hipStream_t stream) {
    const float* query   = (const float*)d_in[0];
    const float* ref_pts = (const float*)d_in[1];
    const float* value   = (const float*)d_in[2];
    const float* vproj_w = (const float*)d_in[5];
    const float* vproj_b = (const float*)d_in[6];
    const float* off_w   = (const float*)d_in[7];
    const float* off_b   = (const float*)d_in[8];
    const float* attn_w  = (const float*)d_in[9];
    const float* attn_b  = (const float*)d_in[10];
    const float* out_w   = (const float*)d_in[11];
    const float* out_b   = (const float*)d_in[12];
    float* out = (float*)d_out;

    bf16* ws = (bf16*)d_ws;
    f16*  v_h     = (f16*)ws;                          // ROWS*256 (f16)
    bf16* oa_bf   = ws     + (size_t)ROWS * 256;       // ROWS*384
    bf16* pre_bf  = oa_bf  + (size_t)ROWS * 384;       // ROWS*256
    bf16* bt_v    = pre_bf + (size_t)ROWS * 256;       // 256*256 (frag order)
    bf16* bt_oa   = bt_v   + 256 * 256;                // 384*256 (frag order)
    bf16* bt_out  = bt_oa  + 384 * 256;                // 256*256 (frag order)
    float* bias_oa = (float*)(bt_out + 256 * 256);     // 384 f32

    dim3 blk(256);

    prep_weights<<<dim3(57), blk, 0, stream>>>(vproj_w, off_w, attn_w, out_w,
                                               off_b, attn_b, bt_v, bt_oa, bt_out, bias_oa);

    gemm_front<<<dim3(680), blk, 0, stream>>>(value, query, bt_v, bt_oa,
                                              vproj_b, bias_oa, v_h, oa_bf);

    msda_sample<<<dim3(5440), blk, 0, stream>>>(v_h, ref_pts, oa_bf, pre_bf);

    gemm_back<<<dim3(340), blk, 0, stream>>>(pre_bf, bt_out, out_b, out);
}